// Round 5
// baseline (135.706 us; speedup 1.0000x reference)
//
#include <hip/hip_runtime.h>
#include <math.h>

#define BATCH   256
#define NFEAT   512
#define DMODEL  1024
#define DHALF   512
#define LN_EPS  1e-5f
#define LDSK    68   // transposed LDS tile stride ([kk][m]); 16B-aligned (+4 pad)

typedef float f2 __attribute__((ext_vector_type(2)));
typedef float f4 __attribute__((ext_vector_type(4)));

// ---------------------------------------------------------------------------
// GEMM, 64x64 tile, 256 threads, 4x4 outputs/thread, split-K, reg-staged
// double buffering (next tile's global loads issued before current compute).
//   C = A[M][K] * op(B);  op(B) = B^T (B:[N][K]) if B_NT else B ([K][N]).
// LDS tiles TRANSPOSED: As[kk][m], Bs[kk][n], stride 68 -> frag loads are one
// ds_read_b128 each (a-frag 16-lane broadcast groups = conflict-free, b-frag
// 2-way = free per m136). SPLIT==1: direct write (+bias/+sigmoid).
// SPLIT>1: partials C[z][M][N].
// ---------------------------------------------------------------------------
template <int M, int N, int K, int SPLIT, bool B_NT, bool BIAS, bool SIG>
__global__ __launch_bounds__(256) void gemm64_kernel(
    const float* __restrict__ A, const float* __restrict__ B,
    const float* __restrict__ bias, float* __restrict__ C) {
  __shared__ __align__(16) float As[64 * LDSK];
  __shared__ __align__(16) float Bs[64 * LDSK];
  constexpr int KC = K / SPLIT;   // K per block
  constexpr int NT = KC / 64;     // k-tiles per block
  const int bm  = blockIdx.x * 64;
  const int bn  = blockIdx.y * 64;
  const int kb  = blockIdx.z * KC;
  const int tid = threadIdx.x;
  const int tx  = tid & 15;   // n-group: cols tx*4..+3
  const int ty  = tid >> 4;   // m-group: rows ty*4..+3
  const int r16 = tid >> 4;   // staging row base (0..15)
  const int c4  = tid & 15;   // staging float4 col (0..15)

  f4 ar[4], br[4];  // staging registers (double-buffer vs LDS)

  auto load_tile = [&](int t) {
#pragma unroll
    for (int jj = 0; jj < 4; ++jj) {
      const int row = r16 + jj * 16;
      ar[jj] = *(const f4*)(&A[(size_t)(bm + row) * K + kb + t * 64 + c4 * 4]);
      if (B_NT)
        br[jj] = *(const f4*)(&B[(size_t)(bn + row) * K + kb + t * 64 + c4 * 4]);
      else
        br[jj] = *(const f4*)(&B[(size_t)(kb + t * 64 + row) * N + bn + c4 * 4]);
    }
  };
  auto store_tile = [&]() {
#pragma unroll
    for (int jj = 0; jj < 4; ++jj) {
      const int row = r16 + jj * 16;
      // A: [m][k] -> As[kk][m] transpose (scalar scatter)
      As[(c4 * 4 + 0) * LDSK + row] = ar[jj].x;
      As[(c4 * 4 + 1) * LDSK + row] = ar[jj].y;
      As[(c4 * 4 + 2) * LDSK + row] = ar[jj].z;
      As[(c4 * 4 + 3) * LDSK + row] = ar[jj].w;
      if (B_NT) {
        Bs[(c4 * 4 + 0) * LDSK + row] = br[jj].x;
        Bs[(c4 * 4 + 1) * LDSK + row] = br[jj].y;
        Bs[(c4 * 4 + 2) * LDSK + row] = br[jj].z;
        Bs[(c4 * 4 + 3) * LDSK + row] = br[jj].w;
      } else {
        *(f4*)(&Bs[row * LDSK + c4 * 4]) = br[jj];  // natural, b128 write
      }
    }
  };

  f2 acc[4][2];
#pragma unroll
  for (int i = 0; i < 4; ++i) { acc[i][0] = (f2)0.f; acc[i][1] = (f2)0.f; }

  load_tile(0);
  store_tile();
  __syncthreads();

  for (int t = 0; t < NT; ++t) {
    if (t + 1 < NT) load_tile(t + 1);  // in flight during compute
#pragma unroll 4
    for (int kk = 0; kk < 64; ++kk) {
      const f4 af = *(const f4*)(&As[kk * LDSK + ty * 4]);
      const f4 bf = *(const f4*)(&Bs[kk * LDSK + tx * 4]);
      const f2 b01 = {bf.x, bf.y};
      const f2 b23 = {bf.z, bf.w};
#pragma unroll
      for (int i = 0; i < 4; ++i) {
        const f2 ai = {af[i], af[i]};
        acc[i][0] += ai * b01;  // contract -> v_pk_fma_f32
        acc[i][1] += ai * b23;
      }
    }
    if (t + 1 < NT) {
      __syncthreads();
      store_tile();
      __syncthreads();
    }
  }

  const int z = blockIdx.z;
  f4 bv = {0.f, 0.f, 0.f, 0.f};
  if (BIAS && SPLIT == 1) bv = *(const f4*)(&bias[bn + tx * 4]);
#pragma unroll
  for (int i = 0; i < 4; ++i) {
    const int m = bm + ty * 4 + i;
    f4 cv = {acc[i][0].x, acc[i][0].y, acc[i][1].x, acc[i][1].y};
    if (SPLIT == 1) {
      if (BIAS) cv += bv;
      if (SIG) {
#pragma unroll
        for (int u = 0; u < 4; ++u) cv[u] = 1.f / (1.f + expf(-cv[u]));
      }
      *(f4*)(&C[(size_t)m * N + bn + tx * 4]) = cv;
    } else {
      *(f4*)(&C[((size_t)z * M + m) * N + bn + tx * 4]) = cv;
    }
  }
}

// ---------------------------------------------------------------------------
// Fused partial-reduce (+bias) + pairwise phase coherence + calcium update.
//   phi[b][i] = sum_z parts[z][b][i] + bp[i]      (PARTS>1; optionally stored)
//   ca[b][i]  = 0.95*prev_ca + (0.05/D) * sum_j |cos(phi_i)cos(phi_j)
//                                                + sin(phi_i)sin(phi_j)|
// One block (512 thr = 8 waves, 2/SIMD for TLP latency hiding) per batch row,
// 2 i's/thread (f2-contiguous). Planar cos/sin LDS tables -> wave-uniform
// b128 broadcast reads (conflict-free); packed-f32 mul/fma; |x| folds into
// the v_add_f32 input modifier; 4 independent accumulator chains.
// ---------------------------------------------------------------------------
template <int PARTS, bool WRITE_PHI>
__global__ __launch_bounds__(512) void coherence_ca_kernel(
    const float* __restrict__ parts,   // PARTS>1: [PARTS][B][D]; else phi [B][D]
    const float* __restrict__ bp, const float* __restrict__ prev_ca,
    float* __restrict__ phi_out, float* __restrict__ ca_out) {
  __shared__ __align__(16) float cc[DMODEL];
  __shared__ __align__(16) float ss[DMODEL];
  const int b   = blockIdx.x;
  const int tid = threadIdx.x;   // owns elements 2*tid, 2*tid+1

  f2 ph = ((const f2*)(parts + (size_t)b * DMODEL))[tid];
  if (PARTS > 1) {
#pragma unroll
    for (int z = 1; z < PARTS; ++z)
      ph += ((const f2*)(parts + ((size_t)z * BATCH + b) * DMODEL))[tid];
    ph += ((const f2*)bp)[tid];
    if (WRITE_PHI) ((f2*)(phi_out + (size_t)b * DMODEL))[tid] = ph;
  }
  float ci[2], si[2];
  sincosf(ph.x, &si[0], &ci[0]);
  sincosf(ph.y, &si[1], &ci[1]);
  *(f2*)(&cc[tid * 2]) = f2{ci[0], ci[1]};
  *(f2*)(&ss[tid * 2]) = f2{si[0], si[1]};
  __syncthreads();

  float accA[2] = {0.f, 0.f};
  float accB[2] = {0.f, 0.f};
#pragma unroll 8
  for (int j4 = 0; j4 < DMODEL; j4 += 4) {
    const f4 cy = *(const f4*)(&cc[j4]);  // wave-uniform broadcast
    const f4 sy = *(const f4*)(&ss[j4]);
    const f2 cy01 = {cy.x, cy.y}, cy23 = {cy.z, cy.w};
    const f2 sy01 = {sy.x, sy.y}, sy23 = {sy.z, sy.w};
#pragma unroll
    for (int u = 0; u < 2; ++u) {
      const f2 cu = {ci[u], ci[u]};
      const f2 su = {si[u], si[u]};
      f2 t = su * sy01; t = cu * cy01 + t;   // pk_mul + pk_fma
      accA[u] += __builtin_fabsf(t.x);       // v_add_f32 with |src| modifier
      accB[u] += __builtin_fabsf(t.y);
      t = su * sy23; t = cu * cy23 + t;
      accA[u] += __builtin_fabsf(t.x);
      accB[u] += __builtin_fabsf(t.y);
    }
  }

  const f2 pc = ((const f2*)(prev_ca + (size_t)b * DMODEL))[tid];
  f2 o;
  o.x = pc.x * 0.95f + (accA[0] + accB[0]) * (0.05f / (float)DMODEL);
  o.y = pc.y * 0.95f + (accA[1] + accB[1]) * (0.05f / (float)DMODEL);
  ((f2*)(ca_out + (size_t)b * DMODEL))[tid] = o;
}

// ---------------------------------------------------------------------------
// Fused epilogue. Reduces coupled partials (PCP) and gate partials (PGP),
// applies bias+sigmoid to gate if GATE_RAW, then
// features = LN(coupled * gate_full + phi) * gamma + beta.
// One block (256 thr) per batch row, 4 cols/thread.
// ---------------------------------------------------------------------------
template <int PCP, int PGP, bool GATE_RAW>
__global__ __launch_bounds__(256) void fused_ln_kernel(
    const float* __restrict__ pC, const float* __restrict__ pG,
    const float* __restrict__ phi, const float* __restrict__ bg,
    const float* __restrict__ gamma, const float* __restrict__ beta,
    float* __restrict__ out) {
  __shared__ float red[2][4];
  const int b   = blockIdx.x;
  const int tid = threadIdx.x;
  float gs[2];
#pragma unroll
  for (int h = 0; h < 2; ++h) {
    const int gi = tid + h * 256;
    float s = 0.f;
#pragma unroll
    for (int z = 0; z < PGP; ++z)
      s += pG[((size_t)z * BATCH + b) * DHALF + gi];
    if (GATE_RAW) {
      s += bg[gi];
      s = 1.f / (1.f + expf(-s));
    }
    gs[h] = s;
  }
  float hv[4];
  float sum = 0.f, sumsq = 0.f;
#pragma unroll
  for (int u = 0; u < 4; ++u) {
    const int n = tid + u * 256;
    float cpl = 0.f;
#pragma unroll
    for (int z = 0; z < PCP; ++z)
      cpl += pC[((size_t)z * BATCH + b) * DMODEL + n];
    const float v = fmaf(cpl, gs[u & 1], phi[(size_t)b * DMODEL + n]);
    hv[u] = v;
    sum += v;
    sumsq = fmaf(v, v, sumsq);
  }
  const int lane = tid & 63;
  const int wid  = tid >> 6;
#pragma unroll
  for (int off = 32; off > 0; off >>= 1) {
    sum   += __shfl_down(sum, off);
    sumsq += __shfl_down(sumsq, off);
  }
  if (lane == 0) { red[0][wid] = sum; red[1][wid] = sumsq; }
  __syncthreads();
  sum   = red[0][0] + red[0][1] + red[0][2] + red[0][3];
  sumsq = red[1][0] + red[1][1] + red[1][2] + red[1][3];
  const float mu   = sum * (1.f / DMODEL);
  const float var  = sumsq * (1.f / DMODEL) - mu * mu;
  const float rstd = rsqrtf(var + LN_EPS);
#pragma unroll
  for (int u = 0; u < 4; ++u) {
    const int n = tid + u * 256;
    out[(size_t)b * DMODEL + n] = (hv[u] - mu) * rstd * gamma[n] + beta[n];
  }
}

// ---------------------------------------------------------------------------
extern "C" void kernel_launch(void* const* d_in, const int* in_sizes, int n_in,
                              void* d_out, int out_size, void* d_ws,
                              size_t ws_size, hipStream_t stream) {
  const float* x       = (const float*)d_in[0];  // [256,512]
  const float* prev_ca = (const float*)d_in[1];  // [256,1024]
  const float* Wp      = (const float*)d_in[2];  // [1024,512]  (NT)
  const float* bp      = (const float*)d_in[3];  // [1024]
  const float* Wg      = (const float*)d_in[4];  // [512,1024]  (NT)
  const float* bg      = (const float*)d_in[5];  // [512]
  const float* W       = (const float*)d_in[6];  // [1024,1024] (NN)
  const float* gamma   = (const float*)d_in[7];  // [1024]
  const float* beta    = (const float*)d_in[8];  // [1024]

  float* out_features = (float*)d_out;                  // [256,1024]
  float* out_ca       = out_features + BATCH * DMODEL;  // [256,1024]
  float* out_W        = out_ca + BATCH * DMODEL;        // [1024,1024]

  const size_t need_main =
      (size_t)(BATCH * DMODEL + 4 * BATCH * DMODEL + 8 * BATCH * DHALF) *
      sizeof(float);                                         // 9 MB
  const size_t need_compact =
      (size_t)(2 * BATCH * DMODEL + BATCH * DHALF) * sizeof(float);  // 2.5 MB

  if (ws_size >= need_main) {
    // --- split-K path: every GEMM grid = 256 blocks (1/CU) ---
    float* ws   = (float*)d_ws;
    float* phi  = ws;                         // 1 MB
    float* pbuf = phi + BATCH * DMODEL;       // 4*[256][1024] = 4 MB
    float* pG   = pbuf + 4 * BATCH * DMODEL;  // 8*[256][512]  = 4 MB
    // 1) phi partials: x @ Wp^T -> pbuf[4][256][1024]
    gemm64_kernel<BATCH, DMODEL, NFEAT, 4, true, false, false>
        <<<dim3(4, 16, 4), 256, 0, stream>>>(x, Wp, nullptr, pbuf);
    // 2) fused: phi = sum+bp (stored), ca = coherence -> out_ca
    coherence_ca_kernel<4, true><<<BATCH, 512, 0, stream>>>(
        pbuf, bp, prev_ca, phi, out_ca);
    // 3) gate partials: ca @ Wg^T -> pG[8][256][512]
    gemm64_kernel<BATCH, DHALF, DMODEL, 8, true, false, false>
        <<<dim3(4, 8, 8), 256, 0, stream>>>(out_ca, Wg, nullptr, pG);
    // 4) coupled partials: phi @ W -> pbuf (reuse)
    gemm64_kernel<BATCH, DMODEL, DMODEL, 4, false, false, false>
        <<<dim3(4, 16, 4), 256, 0, stream>>>(phi, W, nullptr, pbuf);
    // 5) fused reduce + gate sigmoid + LN
    fused_ln_kernel<4, 8, true><<<BATCH, 256, 0, stream>>>(
        pbuf, pG, phi, bg, gamma, beta, out_features);
  } else {
    // --- compact path (2.5 MB): in ws if it fits, else in out_W region
    // (4 MB, safe: only consumed before the final W memcpy overwrites it) ---
    float* scratch = (ws_size >= need_compact) ? (float*)d_ws : out_W;
    float* phi     = scratch;                 // [256,1024]
    float* gate    = phi + BATCH * DMODEL;    // [256,512]
    float* coupled = gate + BATCH * DHALF;    // [256,1024]
    gemm64_kernel<BATCH, DMODEL, NFEAT, 1, true, true, false>
        <<<dim3(4, 16, 1), 256, 0, stream>>>(x, Wp, bp, phi);
    coherence_ca_kernel<1, false><<<BATCH, 512, 0, stream>>>(
        phi, bp, prev_ca, nullptr, out_ca);
    gemm64_kernel<BATCH, DHALF, DMODEL, 1, true, true, true>
        <<<dim3(4, 8, 1), 256, 0, stream>>>(out_ca, Wg, bg, gate);
    gemm64_kernel<BATCH, DMODEL, DMODEL, 1, false, false, false>
        <<<dim3(4, 16, 1), 256, 0, stream>>>(phi, W, nullptr, coupled);
    fused_ln_kernel<1, 1, false><<<BATCH, 256, 0, stream>>>(
        coupled, gate, phi, bg, gamma, beta, out_features);
  }

  // third output: W passthrough (always last — compact path may have used
  // the out_W region as scratch above)
  hipMemcpyAsync(out_W, W, (size_t)DMODEL * DMODEL * sizeof(float),
                 hipMemcpyDeviceToDevice, stream);
}

// Round 7
// 131.912 us; speedup vs baseline: 1.0288x; 1.0288x over previous
//
#include <hip/hip_runtime.h>
#include <math.h>

#define BATCH   256
#define NFEAT   512
#define DMODEL  1024
#define DHALF   512
#define LN_EPS  1e-5f
#define LDSK    68   // transposed LDS tile stride ([kk][m]); 16B-aligned (+4 pad)

typedef float f2 __attribute__((ext_vector_type(2)));
typedef float f4 __attribute__((ext_vector_type(4)));

// ---------------------------------------------------------------------------
// GEMM, 64x64 tile, 256 threads, 4x4 outputs/thread, split-K, reg-staged
// double buffering. C = A[M][K] * op(B); op(B)=B^T (B:[N][K]) if B_NT else B.
// LDS tiles TRANSPOSED: As[kk][m], Bs[kk][n], stride 68 -> frag loads are one
// ds_read_b128 each. SPLIT==1: direct write (+bias/+sigmoid).
// SPLIT>1: partials C[z][M][N].  Grids sized to 512 blocks (2/CU) for TLP.
// COPYW: grid.z has 2 extra slices whose blocks copy W (1024x1024 f32) to
// out_W instead of doing GEMM work — removes the tail memcpy dispatch.
// Requires gridDim.x*gridDim.y == 64 when enabled.
// ---------------------------------------------------------------------------
template <int M, int N, int K, int SPLIT, bool B_NT, bool BIAS, bool SIG,
          bool COPYW>
__global__ __launch_bounds__(256) void gemm64_kernel(
    const float* __restrict__ A, const float* __restrict__ B,
    const float* __restrict__ bias, float* __restrict__ C,
    const f4* __restrict__ cpy_src, f4* __restrict__ cpy_dst) {
  if (COPYW) {
    if (blockIdx.z >= (unsigned)SPLIT) {
      // 128 copy blocks x 2048 f4 = 262144 f4 = 4 MB (W passthrough)
      const int cb = (blockIdx.z - SPLIT) * 64 + blockIdx.y * 4 + blockIdx.x;
      const int base = cb * 2048 + threadIdx.x;
#pragma unroll
      for (int k = 0; k < 8; ++k)
        cpy_dst[base + k * 256] = cpy_src[base + k * 256];
      return;
    }
  }
  __shared__ __align__(16) float As[64 * LDSK];
  __shared__ __align__(16) float Bs[64 * LDSK];
  constexpr int KC = K / SPLIT;   // K per block
  constexpr int NT = KC / 64;     // k-tiles per block
  const int bm  = blockIdx.x * 64;
  const int bn  = blockIdx.y * 64;
  const int kb  = blockIdx.z * KC;
  const int tid = threadIdx.x;
  const int tx  = tid & 15;   // n-group: cols tx*4..+3
  const int ty  = tid >> 4;   // m-group: rows ty*4..+3
  const int r16 = tid >> 4;   // staging row base (0..15)
  const int c4  = tid & 15;   // staging float4 col (0..15)

  f4 ar[4], br[4];  // staging registers

  auto load_tile = [&](int t) {
#pragma unroll
    for (int jj = 0; jj < 4; ++jj) {
      const int row = r16 + jj * 16;
      ar[jj] = *(const f4*)(&A[(size_t)(bm + row) * K + kb + t * 64 + c4 * 4]);
      if (B_NT)
        br[jj] = *(const f4*)(&B[(size_t)(bn + row) * K + kb + t * 64 + c4 * 4]);
      else
        br[jj] = *(const f4*)(&B[(size_t)(kb + t * 64 + row) * N + bn + c4 * 4]);
    }
  };
  auto store_tile = [&]() {
#pragma unroll
    for (int jj = 0; jj < 4; ++jj) {
      const int row = r16 + jj * 16;
      // A: [m][k] -> As[kk][m] transpose (scalar scatter)
      As[(c4 * 4 + 0) * LDSK + row] = ar[jj].x;
      As[(c4 * 4 + 1) * LDSK + row] = ar[jj].y;
      As[(c4 * 4 + 2) * LDSK + row] = ar[jj].z;
      As[(c4 * 4 + 3) * LDSK + row] = ar[jj].w;
      if (B_NT) {
        Bs[(c4 * 4 + 0) * LDSK + row] = br[jj].x;
        Bs[(c4 * 4 + 1) * LDSK + row] = br[jj].y;
        Bs[(c4 * 4 + 2) * LDSK + row] = br[jj].z;
        Bs[(c4 * 4 + 3) * LDSK + row] = br[jj].w;
      } else {
        *(f4*)(&Bs[row * LDSK + c4 * 4]) = br[jj];  // natural, b128 write
      }
    }
  };

  f2 acc[4][2];
#pragma unroll
  for (int i = 0; i < 4; ++i) { acc[i][0] = (f2)0.f; acc[i][1] = (f2)0.f; }

  load_tile(0);
  store_tile();
  __syncthreads();

  for (int t = 0; t < NT; ++t) {
    if (t + 1 < NT) load_tile(t + 1);  // in flight during compute
#pragma unroll 4
    for (int kk = 0; kk < 64; ++kk) {
      const f4 af = *(const f4*)(&As[kk * LDSK + ty * 4]);
      const f4 bf = *(const f4*)(&Bs[kk * LDSK + tx * 4]);
      const f2 b01 = {bf.x, bf.y};
      const f2 b23 = {bf.z, bf.w};
#pragma unroll
      for (int i = 0; i < 4; ++i) {
        const f2 ai = {af[i], af[i]};
        acc[i][0] += ai * b01;  // contract -> v_pk_fma_f32
        acc[i][1] += ai * b23;
      }
    }
    if (t + 1 < NT) {
      __syncthreads();
      store_tile();
      __syncthreads();
    }
  }

  const int z = blockIdx.z;
  f4 bv = {0.f, 0.f, 0.f, 0.f};
  if (BIAS && SPLIT == 1) bv = *(const f4*)(&bias[bn + tx * 4]);
#pragma unroll
  for (int i = 0; i < 4; ++i) {
    const int m = bm + ty * 4 + i;
    f4 cv = {acc[i][0].x, acc[i][0].y, acc[i][1].x, acc[i][1].y};
    if (SPLIT == 1) {
      if (BIAS) cv += bv;
      if (SIG) {
#pragma unroll
        for (int u = 0; u < 4; ++u) cv[u] = 1.f / (1.f + expf(-cv[u]));
      }
      *(f4*)(&C[(size_t)m * N + bn + tx * 4]) = cv;
    } else {
      *(f4*)(&C[((size_t)z * M + m) * N + bn + tx * 4]) = cv;
    }
  }
}

// ---------------------------------------------------------------------------
// Fused partial-reduce (+bias) + pairwise phase coherence + calcium update.
// One block (512 thr = 8 waves, 2/SIMD) per batch row, 2 i's/thread.
// Planar cos/sin LDS tables -> wave-uniform b128 broadcast reads;
// packed-f32 mul/fma; |x| folds into v_add_f32 input modifier.
// VALU floor ~2 instr/(i,j) -> ~6.8 us.
// ---------------------------------------------------------------------------
template <int PARTS, bool WRITE_PHI>
__global__ __launch_bounds__(512) void coherence_ca_kernel(
    const float* __restrict__ parts,   // PARTS>1: [PARTS][B][D]; else phi [B][D]
    const float* __restrict__ bp, const float* __restrict__ prev_ca,
    float* __restrict__ phi_out, float* __restrict__ ca_out) {
  __shared__ __align__(16) float cc[DMODEL];
  __shared__ __align__(16) float ss[DMODEL];
  const int b   = blockIdx.x;
  const int tid = threadIdx.x;   // owns elements 2*tid, 2*tid+1

  f2 ph = ((const f2*)(parts + (size_t)b * DMODEL))[tid];
  if (PARTS > 1) {
#pragma unroll
    for (int z = 1; z < PARTS; ++z)
      ph += ((const f2*)(parts + ((size_t)z * BATCH + b) * DMODEL))[tid];
    ph += ((const f2*)bp)[tid];
    if (WRITE_PHI) ((f2*)(phi_out + (size_t)b * DMODEL))[tid] = ph;
  }
  float ci[2], si[2];
  sincosf(ph.x, &si[0], &ci[0]);
  sincosf(ph.y, &si[1], &ci[1]);
  *(f2*)(&cc[tid * 2]) = f2{ci[0], ci[1]};
  *(f2*)(&ss[tid * 2]) = f2{si[0], si[1]};
  __syncthreads();

  float accA[2] = {0.f, 0.f};
  float accB[2] = {0.f, 0.f};
#pragma unroll 8
  for (int j4 = 0; j4 < DMODEL; j4 += 4) {
    const f4 cy = *(const f4*)(&cc[j4]);  // wave-uniform broadcast
    const f4 sy = *(const f4*)(&ss[j4]);
    const f2 cy01 = {cy.x, cy.y}, cy23 = {cy.z, cy.w};
    const f2 sy01 = {sy.x, sy.y}, sy23 = {sy.z, sy.w};
#pragma unroll
    for (int u = 0; u < 2; ++u) {
      const f2 cu = {ci[u], ci[u]};
      const f2 su = {si[u], si[u]};
      f2 t = su * sy01; t = cu * cy01 + t;   // pk_mul + pk_fma
      accA[u] += __builtin_fabsf(t.x);       // v_add_f32 with |src| modifier
      accB[u] += __builtin_fabsf(t.y);
      t = su * sy23; t = cu * cy23 + t;
      accA[u] += __builtin_fabsf(t.x);
      accB[u] += __builtin_fabsf(t.y);
    }
  }

  const f2 pc = ((const f2*)(prev_ca + (size_t)b * DMODEL))[tid];
  f2 o;
  o.x = pc.x * 0.95f + (accA[0] + accB[0]) * (0.05f / (float)DMODEL);
  o.y = pc.y * 0.95f + (accA[1] + accB[1]) * (0.05f / (float)DMODEL);
  ((f2*)(ca_out + (size_t)b * DMODEL))[tid] = o;
}

// ---------------------------------------------------------------------------
// Fused epilogue: reduce coupled partials (PCP) + gate partials (PGP),
// gate bias+sigmoid if GATE_RAW, features = LN(coupled*gate_full + phi).
// One block (256 thr) per batch row, 4 cols/thread.
// ---------------------------------------------------------------------------
template <int PCP, int PGP, bool GATE_RAW>
__global__ __launch_bounds__(256) void fused_ln_kernel(
    const float* __restrict__ pC, const float* __restrict__ pG,
    const float* __restrict__ phi, const float* __restrict__ bg,
    const float* __restrict__ gamma, const float* __restrict__ beta,
    float* __restrict__ out) {
  __shared__ float red[2][4];
  const int b   = blockIdx.x;
  const int tid = threadIdx.x;
  float gs[2];
#pragma unroll
  for (int h = 0; h < 2; ++h) {
    const int gi = tid + h * 256;
    float s = 0.f;
#pragma unroll
    for (int z = 0; z < PGP; ++z)
      s += pG[((size_t)z * BATCH + b) * DHALF + gi];
    if (GATE_RAW) {
      s += bg[gi];
      s = 1.f / (1.f + expf(-s));
    }
    gs[h] = s;
  }
  float hv[4];
  float sum = 0.f, sumsq = 0.f;
#pragma unroll
  for (int u = 0; u < 4; ++u) {
    const int n = tid + u * 256;
    float cpl = 0.f;
#pragma unroll
    for (int z = 0; z < PCP; ++z)
      cpl += pC[((size_t)z * BATCH + b) * DMODEL + n];
    const float v = fmaf(cpl, gs[u & 1], phi[(size_t)b * DMODEL + n]);
    hv[u] = v;
    sum += v;
    sumsq = fmaf(v, v, sumsq);
  }
  const int lane = tid & 63;
  const int wid  = tid >> 6;
#pragma unroll
  for (int off = 32; off > 0; off >>= 1) {
    sum   += __shfl_down(sum, off);
    sumsq += __shfl_down(sumsq, off);
  }
  if (lane == 0) { red[0][wid] = sum; red[1][wid] = sumsq; }
  __syncthreads();
  sum   = red[0][0] + red[0][1] + red[0][2] + red[0][3];
  sumsq = red[1][0] + red[1][1] + red[1][2] + red[1][3];
  const float mu   = sum * (1.f / DMODEL);
  const float var  = sumsq * (1.f / DMODEL) - mu * mu;
  const float rstd = rsqrtf(var + LN_EPS);
#pragma unroll
  for (int u = 0; u < 4; ++u) {
    const int n = tid + u * 256;
    out[(size_t)b * DMODEL + n] = (hv[u] - mu) * rstd * gamma[n] + beta[n];
  }
}

// ---------------------------------------------------------------------------
extern "C" void kernel_launch(void* const* d_in, const int* in_sizes, int n_in,
                              void* d_out, int out_size, void* d_ws,
                              size_t ws_size, hipStream_t stream) {
  const float* x       = (const float*)d_in[0];  // [256,512]
  const float* prev_ca = (const float*)d_in[1];  // [256,1024]
  const float* Wp      = (const float*)d_in[2];  // [1024,512]  (NT)
  const float* bp      = (const float*)d_in[3];  // [1024]
  const float* Wg      = (const float*)d_in[4];  // [512,1024]  (NT)
  const float* bg      = (const float*)d_in[5];  // [512]
  const float* W       = (const float*)d_in[6];  // [1024,1024] (NN)
  const float* gamma   = (const float*)d_in[7];  // [1024]
  const float* beta    = (const float*)d_in[8];  // [1024]

  float* out_features = (float*)d_out;                  // [256,1024]
  float* out_ca       = out_features + BATCH * DMODEL;  // [256,1024]
  float* out_W        = out_ca + BATCH * DMODEL;        // [1024,1024]

  const size_t need_main =
      (size_t)(BATCH * DMODEL + 8 * BATCH * DMODEL + 16 * BATCH * DHALF) *
      sizeof(float);                                         // ~17.8 MB
  const size_t need_compact =
      (size_t)(2 * BATCH * DMODEL + BATCH * DHALF) * sizeof(float);  // 2.5 MB

  if (ws_size >= need_main) {
    // --- split-K path: every GEMM grid = 512 blocks (2/CU, 2 waves/SIMD) ---
    float* ws   = (float*)d_ws;
    float* phi  = ws;                         // 1 MB
    float* pbuf = phi + BATCH * DMODEL;       // 8*[256][1024] = 8 MB
    float* pG   = pbuf + 8 * BATCH * DMODEL;  // 16*[256][512] = 8 MB
    // 1) phi partials: x @ Wp^T -> pbuf[8][256][1024]   (KC=64, NT=1)
    //    + 2 extra z-slices (128 blocks) copy W -> out_W (overlapped)
    gemm64_kernel<BATCH, DMODEL, NFEAT, 8, true, false, false, true>
        <<<dim3(4, 16, 10), 256, 0, stream>>>(x, Wp, nullptr, pbuf,
                                              (const f4*)W, (f4*)out_W);
    // 2) fused: phi = sum+bp (stored), ca = coherence -> out_ca
    coherence_ca_kernel<8, true><<<BATCH, 512, 0, stream>>>(
        pbuf, bp, prev_ca, phi, out_ca);
    // 3) gate partials: ca @ Wg^T -> pG[16][256][512]   (KC=64, NT=1)
    gemm64_kernel<BATCH, DHALF, DMODEL, 16, true, false, false, false>
        <<<dim3(4, 8, 16), 256, 0, stream>>>(out_ca, Wg, nullptr, pG,
                                             nullptr, nullptr);
    // 4) coupled partials: phi @ W -> pbuf (reuse)      (KC=128, NT=2)
    gemm64_kernel<BATCH, DMODEL, DMODEL, 8, false, false, false, false>
        <<<dim3(4, 16, 8), 256, 0, stream>>>(phi, W, nullptr, pbuf,
                                             nullptr, nullptr);
    // 5) fused reduce + gate sigmoid + LN
    fused_ln_kernel<8, 16, true><<<BATCH, 256, 0, stream>>>(
        pbuf, pG, phi, bg, gamma, beta, out_features);
  } else {
    // --- compact path (2.5 MB): in ws if it fits, else in out_W region
    // (4 MB, safe: only consumed before the final W memcpy overwrites it) ---
    float* scratch = (ws_size >= need_compact) ? (float*)d_ws : out_W;
    float* phi     = scratch;                 // [256,1024]
    float* gate    = phi + BATCH * DMODEL;    // [256,512]
    float* coupled = gate + BATCH * DHALF;    // [256,1024]
    gemm64_kernel<BATCH, DMODEL, NFEAT, 1, true, true, false, false>
        <<<dim3(4, 16, 1), 256, 0, stream>>>(x, Wp, bp, phi, nullptr, nullptr);
    coherence_ca_kernel<1, false><<<BATCH, 512, 0, stream>>>(
        phi, bp, prev_ca, nullptr, out_ca);
    gemm64_kernel<BATCH, DHALF, DMODEL, 1, true, true, true, false>
        <<<dim3(4, 8, 1), 256, 0, stream>>>(out_ca, Wg, bg, gate,
                                            nullptr, nullptr);
    gemm64_kernel<BATCH, DMODEL, DMODEL, 1, false, false, false, false>
        <<<dim3(4, 16, 1), 256, 0, stream>>>(phi, W, nullptr, coupled,
                                             nullptr, nullptr);
    fused_ln_kernel<1, 1, false><<<BATCH, 256, 0, stream>>>(
        coupled, gate, phi, bg, gamma, beta, out_features);
    // W passthrough last (scratch may alias out_W)
    hipMemcpyAsync(out_W, W, (size_t)DMODEL * DMODEL * sizeof(float),
                   hipMemcpyDeviceToDevice, stream);
  }
}